// Round 2
// baseline (2601.410 us; speedup 1.0000x reference)
//
#include <hip/hip_runtime.h>

#define N_ROWS 4096
#define H_DIM  1024
#define V_SIZE 32000

typedef __bf16 bf16x8 __attribute__((ext_vector_type(8)));
typedef float  f32x4  __attribute__((ext_vector_type(4)));

typedef __attribute__((address_space(1))) void* gas_ptr;
typedef __attribute__((address_space(3))) void* las_ptr;

__device__ __forceinline__ unsigned short f2bf(float f) {
  unsigned u = __float_as_uint(f);
  u += 0x7fffu + ((u >> 16) & 1u);
  return (unsigned short)(u >> 16);
}

__global__ void zero_f32(float* __restrict__ p, int n) {
  int i = blockIdx.x * blockDim.x + threadIdx.x;
  if (i < n) p[i] = 0.0f;
}

// fp32 -> bf16 (RNE), 8 elems/thread, grid-stride
__global__ void cvt_bf16(const float* __restrict__ in, unsigned short* __restrict__ out, int n8) {
  int i = blockIdx.x * blockDim.x + threadIdx.x;
  int stride = gridDim.x * blockDim.x;
  for (; i < n8; i += stride) {
    const float4* p = (const float4*)(in + (size_t)i * 8);
    float4 a = p[0];
    float4 b = p[1];
    uint4 o;
    o.x = (unsigned)f2bf(a.x) | ((unsigned)f2bf(a.y) << 16);
    o.y = (unsigned)f2bf(a.z) | ((unsigned)f2bf(a.w) << 16);
    o.z = (unsigned)f2bf(b.x) | ((unsigned)f2bf(b.y) << 16);
    o.w = (unsigned)f2bf(b.z) | ((unsigned)f2bf(b.w) << 16);
    *(uint4*)(out + (size_t)i * 8) = o;
  }
}

// Stage one [128 rows][64 cols] bf16 tile (16KB) via global_load_lds width 16.
// LDS dest is linear (uniform base + lane*16); the st_16x32 swizzle
// (byte ^= ((byte>>9)&1)<<5) is applied by pre-swizzling the GLOBAL source
// address (rule 21: same involution on source and read side).
__device__ __forceinline__ void stage_tile(const unsigned short* g, unsigned row0, unsigned k0,
                                           char* lds_tile, unsigned lane) {
#pragma unroll
  for (unsigned i = 0; i < 16; ++i) {
    unsigned p = i * 1024u + lane * 16u;              // physical LDS byte offset this lane fills
    unsigned q = p ^ (((p >> 9) & 1u) << 5);          // logical linear offset (involution)
    unsigned row = q >> 7;                            // tile row (128B per row)
    unsigned byteoff = q & 127u;                      // byte within row
    char* src = (char*)g + ((size_t)(row0 + row) * H_DIM + k0) * 2 + byteoff;
    __builtin_amdgcn_global_load_lds((gas_ptr)src, (las_ptr)(lds_tile + i * 1024u), 16, 0, 0);
  }
}

// Read one 16x16x32 A/B fragment (8 bf16 per lane) with the same swizzle.
__device__ __forceinline__ bf16x8 ld_frag(const char* lds_tile, unsigned row, unsigned kbyte) {
  unsigned lin = row * 128u + kbyte;
  unsigned phys = lin ^ (((lin >> 9) & 1u) << 5);
  return *(const bf16x8*)(lds_tile + phys);
}

// Fused dual-GEMM + KL partial sums.
// grid = (16 vocab-chunks, 32 row-blocks), 256 threads (4 waves, 2x2 of 64x64).
// Per row n accumulates: Zt = sum exp(t), U = sum exp(t)*(t-s), Zs = sum exp(s).
__global__ __launch_bounds__(256, 2) void fused_kl(
    const unsigned short* __restrict__ xb, const unsigned short* __restrict__ txb,
    const unsigned short* __restrict__ wsb, const unsigned short* __restrict__ wtb,
    float* __restrict__ Zt, float* __restrict__ Uu, float* __restrict__ Zs) {
  __shared__ __align__(16) char smem[65536];
  char* xs = smem;
  char* ts = smem + 16384;
  char* wss = smem + 32768;
  char* wts = smem + 49152;

  const unsigned tid = threadIdx.x;
  const unsigned lane = tid & 63u;
  const unsigned w = tid >> 6;           // wave 0..3
  const unsigned wr = w >> 1, wc = w & 1;
  const unsigned rb = blockIdx.y;        // row-block 0..31
  const unsigned chunk = blockIdx.x;     // vocab chunk 0..15
  const unsigned row0 = rb * 128u;
  // 250 vocab tiles over 16 chunks: first 10 chunks get 16 tiles, rest 15
  const unsigned t_begin = chunk * 15u + (chunk < 10u ? chunk : 10u);
  const unsigned t_count = (chunk < 10u) ? 16u : 15u;

  float zt_acc[16], uu_acc[16], zs_acc[16];
#pragma unroll
  for (int i = 0; i < 16; ++i) { zt_acc[i] = 0.f; uu_acc[i] = 0.f; zs_acc[i] = 0.f; }

  const f32x4 fzero = {0.f, 0.f, 0.f, 0.f};

  for (unsigned vt = 0; vt < t_count; ++vt) {
    const unsigned v0 = (t_begin + vt) * 128u;
    f32x4 acc_s[4][4], acc_t[4][4];
#pragma unroll
    for (int mi = 0; mi < 4; ++mi)
#pragma unroll
      for (int ni = 0; ni < 4; ++ni) { acc_s[mi][ni] = fzero; acc_t[mi][ni] = fzero; }

    for (unsigned kt = 0; kt < 16; ++kt) {
      const unsigned k0 = kt * 64u;
      __syncthreads();  // previous iteration's ds_reads done before overwrite
      if (w == 0)      stage_tile(xb,  row0, k0, xs,  lane);
      else if (w == 1) stage_tile(txb, row0, k0, ts,  lane);
      else if (w == 2) stage_tile(wsb, v0,   k0, wss, lane);
      else             stage_tile(wtb, v0,   k0, wts, lane);
      __syncthreads();  // compiler drains vmcnt(0) before s_barrier -> staging visible

#pragma unroll
      for (int kk = 0; kk < 2; ++kk) {
        const unsigned kb = (unsigned)kk * 64u + ((lane >> 4) << 4);
        bf16x8 ax[4], at[4];
#pragma unroll
        for (int mi = 0; mi < 4; ++mi) {
          unsigned r = wr * 64u + (unsigned)mi * 16u + (lane & 15u);
          ax[mi] = ld_frag(xs, r, kb);
          at[mi] = ld_frag(ts, r, kb);
        }
#pragma unroll
        for (int ni = 0; ni < 4; ++ni) {
          unsigned c = wc * 64u + (unsigned)ni * 16u + (lane & 15u);
          bf16x8 bs = ld_frag(wss, c, kb);
          bf16x8 bt = ld_frag(wts, c, kb);
#pragma unroll
          for (int mi = 0; mi < 4; ++mi) {
            acc_s[mi][ni] = __builtin_amdgcn_mfma_f32_16x16x32_bf16(ax[mi], bs, acc_s[mi][ni], 0, 0, 0);
            acc_t[mi][ni] = __builtin_amdgcn_mfma_f32_16x16x32_bf16(at[mi], bt, acc_t[mi][ni], 0, 0, 0);
          }
        }
      }
    }

    // Epilogue: logits complete for this 128-col tile; accumulate per-lane KL sums.
    // C/D layout: col = lane&15, row = (lane>>4)*4 + j  (m89-verified)
#pragma unroll
    for (int mi = 0; mi < 4; ++mi)
#pragma unroll
      for (int j = 0; j < 4; ++j) {
        float ztl = 0.f, uul = 0.f, zsl = 0.f;
#pragma unroll
        for (int ni = 0; ni < 4; ++ni) {
          float s = acc_s[mi][ni][j];
          float t = acc_t[mi][ni][j];
          float et = __expf(t);
          ztl += et;
          uul += et * (t - s);
          zsl += __expf(s);
        }
        zt_acc[mi * 4 + j] += ztl;
        uu_acc[mi * 4 + j] += uul;
        zs_acc[mi * 4 + j] += zsl;
      }
  }

  // Reduce across the 16 lanes that share each row (xor over low 4 lane bits)
#pragma unroll
  for (int i = 0; i < 16; ++i) {
    float a = zt_acc[i], b = uu_acc[i], c = zs_acc[i];
    a += __shfl_xor(a, 1); a += __shfl_xor(a, 2); a += __shfl_xor(a, 4); a += __shfl_xor(a, 8);
    b += __shfl_xor(b, 1); b += __shfl_xor(b, 2); b += __shfl_xor(b, 4); b += __shfl_xor(b, 8);
    c += __shfl_xor(c, 1); c += __shfl_xor(c, 2); c += __shfl_xor(c, 4); c += __shfl_xor(c, 8);
    zt_acc[i] = a; uu_acc[i] = b; zs_acc[i] = c;
  }

  if ((lane & 15u) == 0) {
    const unsigned g = lane >> 4;  // lane group 0..3 holds rows g*4+j of each 16-row frag
#pragma unroll
    for (int mi = 0; mi < 4; ++mi)
#pragma unroll
      for (int j = 0; j < 4; ++j) {
        unsigned n = row0 + wr * 64u + (unsigned)mi * 16u + g * 4u + (unsigned)j;
        atomicAdd(&Zt[n], zt_acc[mi * 4 + j]);
        atomicAdd(&Uu[n], uu_acc[mi * 4 + j]);
        atomicAdd(&Zs[n], zs_acc[mi * 4 + j]);
      }
  }
}

// KL_n = U/Zt - log Zt + log Zs ; out = mean over N, written as FLOAT32
// (reference output dtype is float32 -> d_out is float*).
__global__ void finalize_kl(const float* __restrict__ Zt, const float* __restrict__ Uu,
                            const float* __restrict__ Zs, float* __restrict__ out) {
  __shared__ float red[4];
  float s = 0.f;
  for (int r = threadIdx.x; r < N_ROWS; r += 256) {
    s += Uu[r] / Zt[r] - __logf(Zt[r]) + __logf(Zs[r]);
  }
  s += __shfl_xor(s, 1); s += __shfl_xor(s, 2); s += __shfl_xor(s, 4);
  s += __shfl_xor(s, 8); s += __shfl_xor(s, 16); s += __shfl_xor(s, 32);
  if ((threadIdx.x & 63) == 0) red[threadIdx.x >> 6] = s;
  __syncthreads();
  if (threadIdx.x == 0) {
    float tot = red[0] + red[1] + red[2] + red[3];
    out[0] = tot / (float)N_ROWS;
  }
}

extern "C" void kernel_launch(void* const* d_in, const int* in_sizes, int n_in,
                              void* d_out, int out_size, void* d_ws, size_t ws_size,
                              hipStream_t stream) {
  const float* x  = (const float*)d_in[0];
  const float* tx = (const float*)d_in[1];
  const float* Ws = (const float*)d_in[2];
  const float* Wt = (const float*)d_in[3];

  char* ws = (char*)d_ws;
  float* Zt = (float*)ws;
  float* Uu = Zt + N_ROWS;
  float* Zs = Uu + N_ROWS;
  unsigned short* xb  = (unsigned short*)(ws + 65536);
  unsigned short* txb = xb  + (size_t)N_ROWS * H_DIM;
  unsigned short* wsb = txb + (size_t)N_ROWS * H_DIM;
  unsigned short* wtb = wsb + (size_t)V_SIZE * H_DIM;

  zero_f32<<<(3 * N_ROWS) / 256, 256, 0, stream>>>(Zt, 3 * N_ROWS);
  cvt_bf16<<<2048, 256, 0, stream>>>(x,  xb,  (N_ROWS * H_DIM) / 8);
  cvt_bf16<<<2048, 256, 0, stream>>>(tx, txb, (N_ROWS * H_DIM) / 8);
  cvt_bf16<<<4096, 256, 0, stream>>>(Ws, wsb, (V_SIZE * H_DIM) / 8);
  cvt_bf16<<<4096, 256, 0, stream>>>(Wt, wtb, (V_SIZE * H_DIM) / 8);
  fused_kl<<<dim3(16, 32), 256, 0, stream>>>(xb, txb, wsb, wtb, Zt, Uu, Zs);
  finalize_kl<<<1, 256, 0, stream>>>(Zt, Uu, Zs, (float*)d_out);
}

// Round 3
// 791.231 us; speedup vs baseline: 3.2878x; 3.2878x over previous
//
#include <hip/hip_runtime.h>

#define N_ROWS 4096
#define H_DIM  1024
#define V_SIZE 32000

typedef __bf16 bf16x8 __attribute__((ext_vector_type(8)));
typedef float  f32x4  __attribute__((ext_vector_type(4)));

typedef __attribute__((address_space(1))) void* gas_ptr;
typedef __attribute__((address_space(3))) void* las_ptr;

__device__ __forceinline__ unsigned short f2bf(float f) {
  unsigned u = __float_as_uint(f);
  u += 0x7fffu + ((u >> 16) & 1u);
  return (unsigned short)(u >> 16);
}

__global__ void zero_f32(float* __restrict__ p, int n) {
  int i = blockIdx.x * blockDim.x + threadIdx.x;
  if (i < n) p[i] = 0.0f;
}

// fp32 -> bf16 (RNE), 8 elems/thread, grid-stride
__global__ void cvt_bf16(const float* __restrict__ in, unsigned short* __restrict__ out, int n8) {
  int i = blockIdx.x * blockDim.x + threadIdx.x;
  int stride = gridDim.x * blockDim.x;
  for (; i < n8; i += stride) {
    const float4* p = (const float4*)(in + (size_t)i * 8);
    float4 a = p[0];
    float4 b = p[1];
    uint4 o;
    o.x = (unsigned)f2bf(a.x) | ((unsigned)f2bf(a.y) << 16);
    o.y = (unsigned)f2bf(a.z) | ((unsigned)f2bf(a.w) << 16);
    o.z = (unsigned)f2bf(b.x) | ((unsigned)f2bf(b.y) << 16);
    o.w = (unsigned)f2bf(b.z) | ((unsigned)f2bf(b.w) << 16);
    *(uint4*)(out + (size_t)i * 8) = o;
  }
}

// Bank-conflict swizzle: XOR bits 4-6 of the byte offset with row bits 0-2
// (row = offset>>7 for 128B rows). Involution (bits 4-6 don't feed 7-9).
// Rows 0-7 spread across all 8 16B slots of a row -> ds_read_b128 with
// 16 consecutive rows is ~4-way instead of 8-way (old st_16x32: rows had
// only 2 slots -> 8-way, measured 6.55e7 conflict cycles).
__device__ __forceinline__ unsigned swz(unsigned a) {
  return a ^ (((a >> 7) & 7u) << 4);
}

// Stage one [128 rows][64 cols] bf16 tile (16KB) via global_load_lds width 16.
// LDS dest must be linear (uniform base + lane*16); apply the swizzle by
// pre-permuting the GLOBAL source address (rule 21: same involution both sides).
__device__ __forceinline__ void stage_tile(const unsigned short* g, unsigned row0, unsigned k0,
                                           char* lds_tile, unsigned lane) {
#pragma unroll
  for (unsigned i = 0; i < 16; ++i) {
    unsigned p = i * 1024u + lane * 16u;   // physical LDS byte offset this lane fills
    unsigned q = swz(p);                   // logical linear offset (involution)
    unsigned row = q >> 7;                 // tile row (128B per row)
    unsigned byteoff = q & 127u;           // byte within row
    char* src = (char*)g + ((size_t)(row0 + row) * H_DIM + k0) * 2 + byteoff;
    __builtin_amdgcn_global_load_lds((gas_ptr)src, (las_ptr)(lds_tile + i * 1024u), 16, 0, 0);
  }
}

// Read one 16x16x32 A/B fragment (8 bf16 per lane) with the same swizzle.
__device__ __forceinline__ bf16x8 ld_frag(const char* lds_tile, unsigned row, unsigned kbyte) {
  unsigned phys = swz(row * 128u + kbyte);
  return *(const bf16x8*)(lds_tile + phys);
}

// Fused dual-GEMM + KL partial sums.
// 1-D grid of 512 blocks, XCD-aware: xcd = b&7 hosts rbs {4*xcd..4*xcd+3} x all
// 16 chunks, so co-resident blocks on an XCD share weight tiles (4x) and x
// tiles (16x) in that XCD's L2.
// 256 threads (4 waves, 2x2 of 64x64 per GEMM).
// Per row n accumulates: Zt = sum exp(t), U = sum exp(t)*(t-s), Zs = sum exp(s).
__global__ __launch_bounds__(256, 2) void fused_kl(
    const unsigned short* __restrict__ xb, const unsigned short* __restrict__ txb,
    const unsigned short* __restrict__ wsb, const unsigned short* __restrict__ wtb,
    float* __restrict__ Zt, float* __restrict__ Uu, float* __restrict__ Zs) {
  __shared__ __align__(16) char smem[65536];
  char* xs = smem;
  char* ts = smem + 16384;
  char* wss = smem + 32768;
  char* wts = smem + 49152;

  const unsigned tid = threadIdx.x;
  const unsigned lane = tid & 63u;
  const unsigned w = tid >> 6;           // wave 0..3
  const unsigned wr = w >> 1, wc = w & 1;

  const unsigned b = blockIdx.x;
  const unsigned rb = (b & 7u) * 4u + ((b >> 3) & 3u);  // row-block 0..31
  const unsigned chunk = b >> 5;                        // vocab chunk 0..15
  const unsigned row0 = rb * 128u;
  // 250 vocab tiles over 16 chunks: first 10 chunks get 16 tiles, rest 15
  const unsigned t_begin = chunk * 15u + (chunk < 10u ? chunk : 10u);
  const unsigned t_count = (chunk < 10u) ? 16u : 15u;

  // Per-lane owned-row accumulators (3 VGPRs, replaces 48-reg arrays that spilled)
  float zt1 = 0.f, uu1 = 0.f, zs1 = 0.f;
  const unsigned c = lane & 15u;   // fragment column this lane holds
  const unsigned g = lane >> 4;    // row group within fragment

  const f32x4 fzero = {0.f, 0.f, 0.f, 0.f};

  for (unsigned vt = 0; vt < t_count; ++vt) {
    const unsigned v0 = (t_begin + vt) * 128u;
    f32x4 acc_s[4][4], acc_t[4][4];
#pragma unroll
    for (int mi = 0; mi < 4; ++mi)
#pragma unroll
      for (int ni = 0; ni < 4; ++ni) { acc_s[mi][ni] = fzero; acc_t[mi][ni] = fzero; }

    for (unsigned kt = 0; kt < 16; ++kt) {
      const unsigned k0 = kt * 64u;
      __syncthreads();  // previous iteration's ds_reads done before overwrite
      if (w == 0)      stage_tile(xb,  row0, k0, xs,  lane);
      else if (w == 1) stage_tile(txb, row0, k0, ts,  lane);
      else if (w == 2) stage_tile(wsb, v0,   k0, wss, lane);
      else             stage_tile(wtb, v0,   k0, wts, lane);
      __syncthreads();  // compiler drains vmcnt(0) before s_barrier -> staging visible

#pragma unroll
      for (int kk = 0; kk < 2; ++kk) {
        const unsigned kb = (unsigned)kk * 64u + (g << 4);
        bf16x8 ax[4], at[4];
#pragma unroll
        for (int mi = 0; mi < 4; ++mi) {
          unsigned r = wr * 64u + (unsigned)mi * 16u + c;
          ax[mi] = ld_frag(xs, r, kb);
          at[mi] = ld_frag(ts, r, kb);
        }
#pragma unroll
        for (int ni = 0; ni < 4; ++ni) {
          unsigned col = wc * 64u + (unsigned)ni * 16u + c;
          bf16x8 bs = ld_frag(wss, col, kb);
          bf16x8 bt = ld_frag(wts, col, kb);
#pragma unroll
          for (int mi = 0; mi < 4; ++mi) {
            acc_s[mi][ni] = __builtin_amdgcn_mfma_f32_16x16x32_bf16(ax[mi], bs, acc_s[mi][ni], 0, 0, 0);
            acc_t[mi][ni] = __builtin_amdgcn_mfma_f32_16x16x32_bf16(at[mi], bt, acc_t[mi][ni], 0, 0, 0);
          }
        }
      }
    }

    // Epilogue: logits complete for this 128-col tile. Accumulate KL partial
    // sums, reducing across the 16 column-lanes immediately and depositing to
    // the owner lane (c == mi*4+j) so only 3 accumulator regs stay live.
    // C/D layout: col = lane&15, row = (lane>>4)*4 + j  (m89-verified)
#pragma unroll
    for (int mi = 0; mi < 4; ++mi)
#pragma unroll
      for (int j = 0; j < 4; ++j) {
        float ztl = 0.f, uul = 0.f, zsl = 0.f;
#pragma unroll
        for (int ni = 0; ni < 4; ++ni) {
          float s = acc_s[mi][ni][j];
          float t = acc_t[mi][ni][j];
          float et = __expf(t);
          ztl += et;
          uul += et * (t - s);
          zsl += __expf(s);
        }
        ztl += __shfl_xor(ztl, 1); ztl += __shfl_xor(ztl, 2);
        ztl += __shfl_xor(ztl, 4); ztl += __shfl_xor(ztl, 8);
        uul += __shfl_xor(uul, 1); uul += __shfl_xor(uul, 2);
        uul += __shfl_xor(uul, 4); uul += __shfl_xor(uul, 8);
        zsl += __shfl_xor(zsl, 1); zsl += __shfl_xor(zsl, 2);
        zsl += __shfl_xor(zsl, 4); zsl += __shfl_xor(zsl, 8);
        if (c == (unsigned)(mi * 4 + j)) { zt1 += ztl; uu1 += uul; zs1 += zsl; }
      }
  }

  // Lane (g,c) owns row: wr*64 + (c>>2)*16 + g*4 + (c&3)  (bijective over 64 rows)
  {
    unsigned n = row0 + wr * 64u + (c >> 2) * 16u + g * 4u + (c & 3u);
    atomicAdd(&Zt[n], zt1);
    atomicAdd(&Uu[n], uu1);
    atomicAdd(&Zs[n], zs1);
  }
}

// KL_n = U/Zt - log Zt + log Zs ; out = mean over N, float32.
__global__ void finalize_kl(const float* __restrict__ Zt, const float* __restrict__ Uu,
                            const float* __restrict__ Zs, float* __restrict__ out) {
  __shared__ float red[4];
  float s = 0.f;
  for (int r = threadIdx.x; r < N_ROWS; r += 256) {
    s += Uu[r] / Zt[r] - __logf(Zt[r]) + __logf(Zs[r]);
  }
  s += __shfl_xor(s, 1); s += __shfl_xor(s, 2); s += __shfl_xor(s, 4);
  s += __shfl_xor(s, 8); s += __shfl_xor(s, 16); s += __shfl_xor(s, 32);
  if ((threadIdx.x & 63) == 0) red[threadIdx.x >> 6] = s;
  __syncthreads();
  if (threadIdx.x == 0) {
    float tot = red[0] + red[1] + red[2] + red[3];
    out[0] = tot / (float)N_ROWS;
  }
}

extern "C" void kernel_launch(void* const* d_in, const int* in_sizes, int n_in,
                              void* d_out, int out_size, void* d_ws, size_t ws_size,
                              hipStream_t stream) {
  const float* x  = (const float*)d_in[0];
  const float* tx = (const float*)d_in[1];
  const float* Ws = (const float*)d_in[2];
  const float* Wt = (const float*)d_in[3];

  char* ws = (char*)d_ws;
  float* Zt = (float*)ws;
  float* Uu = Zt + N_ROWS;
  float* Zs = Uu + N_ROWS;
  unsigned short* xb  = (unsigned short*)(ws + 65536);
  unsigned short* txb = xb  + (size_t)N_ROWS * H_DIM;
  unsigned short* wsb = txb + (size_t)N_ROWS * H_DIM;
  unsigned short* wtb = wsb + (size_t)V_SIZE * H_DIM;

  zero_f32<<<(3 * N_ROWS) / 256, 256, 0, stream>>>(Zt, 3 * N_ROWS);
  cvt_bf16<<<2048, 256, 0, stream>>>(x,  xb,  (N_ROWS * H_DIM) / 8);
  cvt_bf16<<<2048, 256, 0, stream>>>(tx, txb, (N_ROWS * H_DIM) / 8);
  cvt_bf16<<<4096, 256, 0, stream>>>(Ws, wsb, (V_SIZE * H_DIM) / 8);
  cvt_bf16<<<4096, 256, 0, stream>>>(Wt, wtb, (V_SIZE * H_DIM) / 8);
  fused_kl<<<512, 256, 0, stream>>>(xb, txb, wsb, wtb, Zt, Uu, Zs);
  finalize_kl<<<1, 256, 0, stream>>>(Zt, Uu, Zs, (float*)d_out);
}